// Round 2
// baseline (757.337 us; speedup 1.0000x reference)
//
#include <hip/hip_runtime.h>
#include <hip/hip_bf16.h>

typedef __attribute__((ext_vector_type(8))) short bf16x8;
typedef __attribute__((ext_vector_type(4))) float f32x4;

__device__ __forceinline__ unsigned short f2bf(float f) {
  unsigned u = __builtin_bit_cast(unsigned, f);
  u += 0x7FFFu + ((u >> 16) & 1u);   // round-to-nearest-even (inputs finite)
  return (unsigned short)(u >> 16);
}

#define HW    2304
#define KDIM  2304
#define NCOLS 1024
#define OUTN  1024
#define KPROJ 32768

// workspace offsets (bytes)
#define WS_T  0
#define WS_PT 294912
#define WS_A  5013504
#define WS_FT 5210112

// ---------------- prep: t[p][r] = sum_s core2[r,h,s]*core3[s,w] ----------------
__global__ void k_t(const float* __restrict__ core2, const float* __restrict__ core3,
                    float* __restrict__ tbuf) {
  int idx = blockIdx.x * 256 + threadIdx.x;
  if (idx >= HW * 32) return;
  int p = idx >> 5, r = idx & 31;
  int h = p / 48, w = p - h * 48;
  float s = 0.f;
#pragma unroll
  for (int si = 0; si < 32; ++si)
    s += core2[(r * 48 + h) * 32 + si] * core3[si * 48 + w];
  tbuf[p * 32 + r] = s;
}

// ---------------- prep: PT[col][p] = bf16(t[p,r]*t[p,q]);  A[d][col] = a[d,r]*a[d,q]
__global__ void k_pa(const float* __restrict__ tbuf, const float* __restrict__ core1,
                     unsigned short* __restrict__ PT, float* __restrict__ Abuf) {
  int idx = blockIdx.x * 256 + threadIdx.x;
  const int PTN = NCOLS * HW;
  if (idx < PTN) {
    int col = idx / HW, p = idx - col * HW;
    int r = col >> 5, q = col & 31;
    float v = tbuf[p * 32 + r] * tbuf[p * 32 + q];
    PT[col * HW + p] = f2bf(v);
  } else {
    int j = idx - PTN;
    if (j < 48 * 1024) {
      int col = j & 1023;
      int d = j >> 10;
      int r = col >> 5, q = col & 31;
      Abuf[j] = core1[d * 32 + r] * core1[d * 32 + q];
    }
  }
}

// ---------------- main GEMM: S = (x*x) @ P^T-cols, fused d-reduction epilogue ----
// BM=192 (4 d-groups), BN=256, BK=64, 512 threads (8 waves: 4 wr x 2 wc)
#define SM_A0 0
#define SM_A1 24576
#define SM_B0 49152
#define SM_B1 81920
#define SM_TOTAL 114688

__global__ __launch_bounds__(512, 2) void k_gemm(const float* __restrict__ x,
    const unsigned short* __restrict__ PT, const float* __restrict__ Abuf,
    float* __restrict__ fT) {
  extern __shared__ char smem[];
  const int tid  = threadIdx.x;
  const int lane = tid & 63;
  const int w    = tid >> 6;
  const int wr   = w >> 1, wc = w & 1;

  int bid = blockIdx.x;
  int swz = (bid & 7) * 64 + (bid >> 3);   // XCD-aware, bijective (512 % 8 == 0)
  const int mt = swz >> 2, nt = swz & 3;
  const int m0 = mt * 192, n0 = nt * 256;

  // staging geometry: thread owns 16B units (8 bf16) at fixed k8, rows srow+64*i
  const int srow = tid >> 3;
  const int k8   = tid & 7;
  const int swzm = (srow & 7) << 4;

  int ldsA_off[3], ldsB_off[4];
#pragma unroll
  for (int i = 0; i < 3; ++i) ldsA_off[i] = (srow + 64 * i) * 128 + ((k8 * 16) ^ swzm);
#pragma unroll
  for (int i = 0; i < 4; ++i) ldsB_off[i] = (srow + 64 * i) * 128 + ((k8 * 16) ^ swzm);

  const float* gA[3];
  const unsigned short* gB[4];
#pragma unroll
  for (int i = 0; i < 3; ++i) gA[i] = x  + (size_t)(m0 + srow + 64 * i) * KDIM + k8 * 8;
#pragma unroll
  for (int i = 0; i < 4; ++i) gB[i] = PT + (size_t)(n0 + srow + 64 * i) * KDIM + k8 * 8;

  f32x4 acc[3][8];
#pragma unroll
  for (int f = 0; f < 3; ++f)
#pragma unroll
    for (int fn = 0; fn < 8; ++fn)
#pragma unroll
      for (int j = 0; j < 4; ++j) acc[f][fn][j] = 0.f;

  float4 ar[3][2];
  uint4  br[4];

  // prologue: stage k0 = 0 into buffer 0
#pragma unroll
  for (int i = 0; i < 3; ++i) {
    ar[i][0] = *(const float4*)(gA[i]);
    ar[i][1] = *(const float4*)(gA[i] + 4);
  }
#pragma unroll
  for (int i = 0; i < 4; ++i) br[i] = *(const uint4*)(gB[i]);
  {
    char* sA = smem + SM_A0;
    char* sB = smem + SM_B0;
#pragma unroll
    for (int i = 0; i < 3; ++i) {
      uint4 pk;
      pk.x = (unsigned)f2bf(ar[i][0].x * ar[i][0].x) | ((unsigned)f2bf(ar[i][0].y * ar[i][0].y) << 16);
      pk.y = (unsigned)f2bf(ar[i][0].z * ar[i][0].z) | ((unsigned)f2bf(ar[i][0].w * ar[i][0].w) << 16);
      pk.z = (unsigned)f2bf(ar[i][1].x * ar[i][1].x) | ((unsigned)f2bf(ar[i][1].y * ar[i][1].y) << 16);
      pk.w = (unsigned)f2bf(ar[i][1].z * ar[i][1].z) | ((unsigned)f2bf(ar[i][1].w * ar[i][1].w) << 16);
      *(uint4*)(sA + ldsA_off[i]) = pk;
    }
#pragma unroll
    for (int i = 0; i < 4; ++i) *(uint4*)(sB + ldsB_off[i]) = br[i];
  }
  __syncthreads();

  int cur = 0;
  const int arow = wr * 48 + (lane & 15);
  const int bcol = wc * 128 + (lane & 15);
  const int lxor = lane & 7;
  const int lgrp = lane >> 4;

  for (int t = 0; t < 36; ++t) {
    if (t < 35) {
      const int k0 = (t + 1) * 64;
#pragma unroll
      for (int i = 0; i < 3; ++i) {
        ar[i][0] = *(const float4*)(gA[i] + k0);
        ar[i][1] = *(const float4*)(gA[i] + k0 + 4);
      }
#pragma unroll
      for (int i = 0; i < 4; ++i) br[i] = *(const uint4*)(gB[i] + k0);
    }
    // compute current buffer
    {
      const char* sA = smem + (cur ? SM_A1 : SM_A0);
      const char* sB = smem + (cur ? SM_B1 : SM_B0);
#pragma unroll
      for (int ks = 0; ks < 2; ++ks) {
        const int xo = (((ks << 2) + lgrp) ^ lxor) << 4;   // swizzled 16B-unit offset
        bf16x8 af[3];
#pragma unroll
        for (int f = 0; f < 3; ++f)
          af[f] = *(const bf16x8*)(sA + (arow + f * 16) * 128 + xo);
#pragma unroll
        for (int fn = 0; fn < 8; ++fn) {
          bf16x8 bf = *(const bf16x8*)(sB + (bcol + fn * 16) * 128 + xo);
#pragma unroll
          for (int f = 0; f < 3; ++f)
            acc[f][fn] = __builtin_amdgcn_mfma_f32_16x16x32_bf16(af[f], bf, acc[f][fn], 0, 0, 0);
        }
      }
    }
    if (t < 35) {
      char* sA = smem + (cur ? SM_A0 : SM_A1);
      char* sB = smem + (cur ? SM_B0 : SM_B1);
#pragma unroll
      for (int i = 0; i < 3; ++i) {
        uint4 pk;
        pk.x = (unsigned)f2bf(ar[i][0].x * ar[i][0].x) | ((unsigned)f2bf(ar[i][0].y * ar[i][0].y) << 16);
        pk.y = (unsigned)f2bf(ar[i][0].z * ar[i][0].z) | ((unsigned)f2bf(ar[i][0].w * ar[i][0].w) << 16);
        pk.z = (unsigned)f2bf(ar[i][1].x * ar[i][1].x) | ((unsigned)f2bf(ar[i][1].y * ar[i][1].y) << 16);
        pk.w = (unsigned)f2bf(ar[i][1].z * ar[i][1].z) | ((unsigned)f2bf(ar[i][1].w * ar[i][1].w) << 16);
        *(uint4*)(sA + ldsA_off[i]) = pk;
      }
#pragma unroll
      for (int i = 0; i < 4; ++i) *(uint4*)(sB + ldsB_off[i]) = br[i];
      __syncthreads();
      cur ^= 1;
    }
  }

  // epilogue: scale by A[d,col], reduce over d (in-reg + cross-lane), write feats^T
  const int nIdx = mt * 4 + wr;          // global n = b*32 + c
  const int bI = nIdx >> 5, cI = nIdx & 31;
  const int g4 = lgrp * 4;
  float gvals[8];
#pragma unroll
  for (int fn = 0; fn < 8; ++fn) {
    int colg = n0 + wc * 128 + fn * 16 + (lane & 15);
    float s = 0.f;
#pragma unroll
    for (int f = 0; f < 3; ++f) {
#pragma unroll
      for (int j = 0; j < 4; ++j) {
        int d = f * 16 + g4 + j;
        s += acc[f][fn][j] * Abuf[d * 1024 + colg];
      }
    }
    s += __shfl_xor(s, 16);
    s += __shfl_xor(s, 32);
    gvals[fn] = s;
  }
  if (lgrp == 0) {   // lanes 0..15 write
#pragma unroll
    for (int fn = 0; fn < 8; ++fn) {
      int colg = n0 + wc * 128 + fn * 16 + lane;
      fT[(size_t)(cI * 1024 + colg) * 16 + bI] = gvals[fn];
    }
  }
}

// ---------------- out init: out[b,o] = proj_b[o] ----------------
__global__ void k_init_out(const float* __restrict__ pb, float* __restrict__ out) {
  int i = blockIdx.x * 256 + threadIdx.x;
  if (i < 16 * OUTN) out[i] = pb[i & (OUTN - 1)];
}

// ---------------- projection: out[b,o] += sum_k fT[k,b] * W[o,k] ----------------
__global__ __launch_bounds__(256, 2) void k_proj(const float* __restrict__ W,
    const float* __restrict__ fT, float* __restrict__ out) {
  int tid = threadIdx.x;
  int lane = tid & 63, wv = tid >> 6;
  int g  = blockIdx.x * 4 + wv;    // 0..2047
  int og = g >> 3, ks = g & 7;
  int o0 = og * 4;
  int kb = ks * 4096 + lane * 4;

  float acc[64];
#pragma unroll
  for (int i = 0; i < 64; ++i) acc[i] = 0.f;

  for (int i = 0; i < 16; ++i) {
    int k = kb + i * 256;
    float4 ft[16];
#pragma unroll
    for (int j = 0; j < 16; ++j) ft[j] = *(const float4*)(fT + (size_t)k * 16 + j * 4);
#pragma unroll
    for (int oo = 0; oo < 4; ++oo) {
      float4 wv4 = *(const float4*)(W + (size_t)(o0 + oo) * KPROJ + k);
      float wj[4] = {wv4.x, wv4.y, wv4.z, wv4.w};
#pragma unroll
      for (int j2 = 0; j2 < 4; ++j2) {
#pragma unroll
        for (int bq = 0; bq < 4; ++bq) {
          float4 fv = ft[j2 * 4 + bq];
          acc[oo * 16 + bq * 4 + 0] += wj[j2] * fv.x;
          acc[oo * 16 + bq * 4 + 1] += wj[j2] * fv.y;
          acc[oo * 16 + bq * 4 + 2] += wj[j2] * fv.z;
          acc[oo * 16 + bq * 4 + 3] += wj[j2] * fv.w;
        }
      }
    }
  }
#pragma unroll
  for (int m = 1; m < 64; m <<= 1)
#pragma unroll
    for (int e = 0; e < 64; ++e) acc[e] += __shfl_xor(acc[e], m);

  int b = lane & 15, j = lane >> 4;
  atomicAdd(&out[b * OUTN + o0 + j], acc[j * 16 + b]);
}

extern "C" void kernel_launch(void* const* d_in, const int* in_sizes, int n_in,
                              void* d_out, int out_size, void* d_ws, size_t ws_size,
                              hipStream_t stream) {
  const float* x     = (const float*)d_in[0];
  const float* core1 = (const float*)d_in[1];
  const float* core2 = (const float*)d_in[2];
  const float* core3 = (const float*)d_in[3];
  const float* projw = (const float*)d_in[4];
  const float* projb = (const float*)d_in[5];
  float* out = (float*)d_out;
  char*  ws  = (char*)d_ws;

  float*          tbuf = (float*)(ws + WS_T);
  unsigned short* PT   = (unsigned short*)(ws + WS_PT);
  float*          Abuf = (float*)(ws + WS_A);
  float*          fT   = (float*)(ws + WS_FT);

  k_t<<<288, 256, 0, stream>>>(core2, core3, tbuf);
  k_pa<<<9408, 256, 0, stream>>>(tbuf, core1, PT, Abuf);
  k_gemm<<<512, 512, SM_TOTAL, stream>>>(x, PT, Abuf, fT);
  k_init_out<<<64, 256, 0, stream>>>(projb, out);
  k_proj<<<512, 256, 0, stream>>>(projw, fT, out);
}